// Round 1
// baseline (505.154 us; speedup 1.0000x reference)
//
#include <hip/hip_runtime.h>
#include <math.h>

// Problem constants
#define Bq 4096
#define Nq 32
#define Eq 5
#define Fq 64
#define Uq 128

constexpr int ADJ_ELEMS  = Bq * Nq * Nq * Eq;   // 20,971,520
constexpr int NODE_ELEMS = Bq * Nq * Fq;        // 8,388,608
constexpr int OUT_OFF    = ADJ_ELEMS + NODE_ELEMS; // 29,360,128
constexpr int ADJ_B  = Nq * Nq * Eq;  // 5120 floats per batch
constexpr int NODE_B = Nq * Fq;       // 2048
constexpr int OUT_B  = Nq * Uq;       // 4096
constexpr int K1   = (Eq - 1) * Fq;   // 256  (k = e*64 + f)
// Wcat rows: k<256 -> W1 flat [k][128]; k in [256,320) -> W2[k-256][128]

// XOR swizzle for the A tile: row i, col c (c = j*4+e', 0..127).
// Spreads the fixed-c-across-i read pattern over all 32 banks; bijective per row.
__device__ __forceinline__ int a2idx(int i, int c) {
    return i * 128 + (c ^ ((((i) & 7) << 2) | (((i) >> 3) & 3)));
}

__global__ __launch_bounds__(256, 2) void gcn_kernel(
    const float* __restrict__ adj, const float* __restrict__ node,
    const float* __restrict__ W1, const float* __restrict__ b1,
    const float* __restrict__ W2, const float* __restrict__ b2,
    float* __restrict__ out)
{
    __shared__ float A2f[Nq * 128];       // 16 KB: A2[i][j*4+e'] (swizzled), e'=e-1
    __shared__ float node_lds[Nq][Fq];    // 8 KB : [i][f]
    __shared__ float Gt[K1 * Nq];         // 32 KB: Gt[k][i], k = e*64+f (k<256)
    __shared__ float rowsum[Nq][4];       // 0.5 KB: sum_j adjacency[b,i,j,e+1]

    const int b = blockIdx.x;
    const int t = threadIdx.x;

    // ---------------- Phase 1a: adjacency copy + stage ----------------
    const float* adj_b  = adj + (size_t)b * ADJ_B;
    float*       out_adj = out + (size_t)b * ADJ_B;
    #pragma unroll
    for (int it = 0; it < 5; ++it) {
        const int fi = (t + it * 256) * 4;          // 0..5116
        float4 v = *(const float4*)(adj_b + fi);
        *(float4*)(out_adj + fi) = v;
        float vals[4] = {v.x, v.y, v.z, v.w};
        #pragma unroll
        for (int r = 0; r < 4; ++r) {
            const int idx = fi + r;                 // i*160 + j*5 + e
            const int e  = idx % 5;
            const int ij = idx / 5;                 // i*32 + j
            if (e > 0) {
                const int i = ij >> 5, j = ij & 31;
                A2f[a2idx(i, j * 4 + (e - 1))] = vals[r];
            }
        }
    }

    // ---------------- Phase 1b: node copy + stage ----------------
    const float* node_b  = node + (size_t)b * NODE_B;
    float*       out_node = out + ADJ_ELEMS + (size_t)b * NODE_B;
    #pragma unroll
    for (int it = 0; it < 2; ++it) {
        const int fi = (t + it * 256) * 4;          // 0..2044
        float4 v = *(const float4*)(node_b + fi);
        *(float4*)(out_node + fi) = v;
        *(float4*)(&node_lds[0][0] + fi) = v;
    }
    __syncthreads();

    // ---------------- Phase 2: Gt[k][i] = sum_j A[i,j,e]*node[j,f] ----------------
    {
        const int i  = t & 31;          // this lane's output column (conflict-free writes)
        const int k0 = (t >> 5) * 32;   // 8 groups of 32 consecutive k
        const int e  = k0 >> 6;         // 0..3 (k-block lies inside one e)
        const int f0 = k0 & 63;         // 0 or 32
        float acc[32];
        #pragma unroll
        for (int kk = 0; kk < 32; ++kk) acc[kk] = 0.f;
        #pragma unroll 4
        for (int j = 0; j < 32; ++j) {
            const float a = A2f[a2idx(i, j * 4 + e)];
            const float4* nrow = (const float4*)(&node_lds[j][f0]); // broadcast within group
            #pragma unroll
            for (int q = 0; q < 8; ++q) {
                float4 nv = nrow[q];
                acc[q*4+0] = fmaf(a, nv.x, acc[q*4+0]);
                acc[q*4+1] = fmaf(a, nv.y, acc[q*4+1]);
                acc[q*4+2] = fmaf(a, nv.z, acc[q*4+2]);
                acc[q*4+3] = fmaf(a, nv.w, acc[q*4+3]);
            }
        }
        #pragma unroll
        for (int kk = 0; kk < 32; ++kk) Gt[(k0 + kk) * 32 + i] = acc[kk]; // bank = i, conflict-free
    }

    // rowsum for the b1-through-adjacency term (b1 is zeros in the bench, but be exact)
    if (t < 128) {
        const int i = t >> 2, e = t & 3;
        float s = 0.f;
        #pragma unroll 4
        for (int j = 0; j < 32; ++j) s += A2f[a2idx(i, j * 4 + e)];
        rowsum[i][e] = s;
    }
    __syncthreads();

    // ---------------- Phase 3: out[i,u] = sum_k G'[i,k]*Wcat[k,u] + bias; tanh ----------------
    const int u0 = (t & 31) * 4;   // 32 u-groups (coalesced W loads within half-wave)
    const int i0 = (t >> 5) * 4;   // 8 i-groups (broadcast Gt reads)

    float acc[4][4];
    // init: bias_eff[i][u] = sum_e rowsum[i][e]*b1[e][u] + b2[u]
    {
        const float4 vb2 = *(const float4*)(b2 + u0);
        #pragma unroll
        for (int ii = 0; ii < 4; ++ii) {
            acc[ii][0] = vb2.x; acc[ii][1] = vb2.y; acc[ii][2] = vb2.z; acc[ii][3] = vb2.w;
        }
        #pragma unroll
        for (int e = 0; e < 4; ++e) {
            const float4 vb1 = *(const float4*)(b1 + e * Uq + u0);
            #pragma unroll
            for (int ii = 0; ii < 4; ++ii) {
                const float rs = rowsum[i0 + ii][e];
                acc[ii][0] = fmaf(rs, vb1.x, acc[ii][0]);
                acc[ii][1] = fmaf(rs, vb1.y, acc[ii][1]);
                acc[ii][2] = fmaf(rs, vb1.z, acc[ii][2]);
                acc[ii][3] = fmaf(rs, vb1.w, acc[ii][3]);
            }
        }
    }

    // main contraction over k<256 (W1 part): 1 LDS b128 (broadcast) + 1 global dwordx4 + 16 FMA
    #pragma unroll 4
    for (int k = 0; k < K1; ++k) {
        const float4 g = *(const float4*)(&Gt[k * 32 + i0]);
        const float4 w = *(const float4*)(W1 + k * Uq + u0);
        acc[0][0] = fmaf(g.x, w.x, acc[0][0]); acc[0][1] = fmaf(g.x, w.y, acc[0][1]);
        acc[0][2] = fmaf(g.x, w.z, acc[0][2]); acc[0][3] = fmaf(g.x, w.w, acc[0][3]);
        acc[1][0] = fmaf(g.y, w.x, acc[1][0]); acc[1][1] = fmaf(g.y, w.y, acc[1][1]);
        acc[1][2] = fmaf(g.y, w.z, acc[1][2]); acc[1][3] = fmaf(g.y, w.w, acc[1][3]);
        acc[2][0] = fmaf(g.z, w.x, acc[2][0]); acc[2][1] = fmaf(g.z, w.y, acc[2][1]);
        acc[2][2] = fmaf(g.z, w.z, acc[2][2]); acc[2][3] = fmaf(g.z, w.w, acc[2][3]);
        acc[3][0] = fmaf(g.w, w.x, acc[3][0]); acc[3][1] = fmaf(g.w, w.y, acc[3][1]);
        acc[3][2] = fmaf(g.w, w.z, acc[3][2]); acc[3][3] = fmaf(g.w, w.w, acc[3][3]);
    }
    // self-loop part k in [256,320): G'[i][k] = node[i][f], broadcast scalar LDS reads
    #pragma unroll 4
    for (int f = 0; f < Fq; ++f) {
        const float4 w = *(const float4*)(W2 + f * Uq + u0);
        const float g0 = node_lds[i0 + 0][f];
        const float g1 = node_lds[i0 + 1][f];
        const float g2 = node_lds[i0 + 2][f];
        const float g3 = node_lds[i0 + 3][f];
        acc[0][0] = fmaf(g0, w.x, acc[0][0]); acc[0][1] = fmaf(g0, w.y, acc[0][1]);
        acc[0][2] = fmaf(g0, w.z, acc[0][2]); acc[0][3] = fmaf(g0, w.w, acc[0][3]);
        acc[1][0] = fmaf(g1, w.x, acc[1][0]); acc[1][1] = fmaf(g1, w.y, acc[1][1]);
        acc[1][2] = fmaf(g1, w.z, acc[1][2]); acc[1][3] = fmaf(g1, w.w, acc[1][3]);
        acc[2][0] = fmaf(g2, w.x, acc[2][0]); acc[2][1] = fmaf(g2, w.y, acc[2][1]);
        acc[2][2] = fmaf(g2, w.z, acc[2][2]); acc[2][3] = fmaf(g2, w.w, acc[2][3]);
        acc[3][0] = fmaf(g3, w.x, acc[3][0]); acc[3][1] = fmaf(g3, w.y, acc[3][1]);
        acc[3][2] = fmaf(g3, w.z, acc[3][2]); acc[3][3] = fmaf(g3, w.w, acc[3][3]);
    }

    // tanh + store (coalesced float4 rows)
    float* out_b = out + OUT_OFF + (size_t)b * OUT_B;
    #pragma unroll
    for (int ii = 0; ii < 4; ++ii) {
        float4 v;
        v.x = tanhf(acc[ii][0]); v.y = tanhf(acc[ii][1]);
        v.z = tanhf(acc[ii][2]); v.w = tanhf(acc[ii][3]);
        *(float4*)(out_b + (size_t)(i0 + ii) * Uq + u0) = v;
    }
}

extern "C" void kernel_launch(void* const* d_in, const int* in_sizes, int n_in,
                              void* d_out, int out_size, void* d_ws, size_t ws_size,
                              hipStream_t stream) {
    const float* adj  = (const float*)d_in[0];
    const float* node = (const float*)d_in[1];
    const float* W1   = (const float*)d_in[2];
    const float* b1   = (const float*)d_in[3];
    const float* W2   = (const float*)d_in[4];
    const float* b2   = (const float*)d_in[5];
    float* out = (float*)d_out;
    hipLaunchKernelGGL(gcn_kernel, dim3(Bq), dim3(256), 0, stream,
                       adj, node, W1, b1, W2, b2, out);
}

// Round 2
// 357.177 us; speedup vs baseline: 1.4143x; 1.4143x over previous
//
#include <hip/hip_runtime.h>
#include <math.h>

#define Bq 4096
#define Nq 32
#define Eq 5
#define Fq 64
#define Uq 128

constexpr int ADJ_ELEMS  = Bq * Nq * Nq * Eq;      // 20,971,520
constexpr int NODE_ELEMS = Bq * Nq * Fq;           // 8,388,608
constexpr int OUT_OFF    = ADJ_ELEMS + NODE_ELEMS; // 29,360,128
constexpr int ADJ_B  = Nq * Nq * Eq;  // 5120 floats per batch
constexpr int NODE_B = Nq * Fq;       // 2048
constexpr int OUT_B  = Nq * Uq;       // 4096
constexpr int KTOT = 320;             // 4*64 (A@node part) + 64 (self-loop/node part)
constexpr int GPAD = 328;             // bf16 row stride for G hi/lo (328*2=656B, 16B-aligned, bank-staggered)
constexpr int NKQ  = KTOT / 32;       // 10 K-steps of 32
constexpr int NNQ  = Uq / 16;         // 8 col-tiles of 16
constexpr int WF_ELEMS = NKQ * NNQ * 64 * 8;  // 40960 ushorts per table (81,920 B)

typedef __attribute__((ext_vector_type(8))) short bf16x8;  // 8 bf16 = 4 VGPRs
typedef __attribute__((ext_vector_type(4))) float f32x4;

__device__ __forceinline__ ushort f2bf(float x) {        // RNE fp32->bf16
    uint u = __float_as_uint(x);
    return (ushort)((u + 0x7FFF + ((u >> 16) & 1)) >> 16);
}
__device__ __forceinline__ float bf2f(ushort h) { return __uint_as_float(((uint)h) << 16); }

// XOR swizzle for the fp32 A tile: row i, col c (c = j*4+e'), conflict-free column reads.
__device__ __forceinline__ int a2idx(int i, int c) {
    return i * 128 + (c ^ ((((i) & 7) << 2) | (((i) >> 3) & 3)));
}

// ---------------------------------------------------------------------------
// Wcat -> B-fragment tables (hi/lo bf16) in d_ws, laid out so a wave's b-frag
// for tile (kq,nq) is one coalesced 16B/lane load:
//   lane l supplies B[kq*32 + (l>>4)*8 + e][nq*16 + (l&15)], e=0..7
//   slot = ((kq*8+nq)*64 + l)*8 + e
// ---------------------------------------------------------------------------
__global__ void wfrag_kernel(const float* __restrict__ W1, const float* __restrict__ W2,
                             ushort* __restrict__ wfH, ushort* __restrict__ wfL) {
    const int tid = blockIdx.x * 256 + threadIdx.x;
    if (tid >= WF_ELEMS) return;
    const int k = tid >> 7;      // 0..319
    const int u = tid & 127;     // 0..127
    const float w = (k < 256) ? W1[k * Uq + u] : W2[(k - 256) * Uq + u];
    const ushort h = f2bf(w);
    const ushort lo = f2bf(w - bf2f(h));
    const int kq = k >> 5, rem = k & 31;
    const int lane = ((rem >> 3) << 4) | (u & 15);
    const int nq = u >> 4;
    const int e = rem & 7;
    const int slot = (((kq * NNQ + nq) * 64 + lane) << 3) + e;
    wfH[slot] = h;
    wfL[slot] = lo;
}

// ---------------------------------------------------------------------------
// Main fused kernel: one block per batch.
//   phase1 : load adj+node, copy to out, stage A2f(fp32,swz)+node(fp32) in LDS
//   phase2a: GEMM1 fp32 VALU  G[i][k] = sum_j A_e[i][j]*node[j][f]  (+rowsum)
//   phase2b: pack G -> bf16 hi/lo into LDS (unioned over A2f/node region)
//   phase3 : GEMM2 via 16x16x32 bf16 MFMA, 3-way split (hh + hl + lh)
// ---------------------------------------------------------------------------
__global__ __launch_bounds__(256, 3) void gcn_kernel(
    const float* __restrict__ adj, const float* __restrict__ node,
    const float* __restrict__ b1, const float* __restrict__ b2,
    const ushort* __restrict__ wfH, const ushort* __restrict__ wfL,
    float* __restrict__ out)
{
    // Union: phases 1-2a use fp32 A2f[32*128] (16KB) + node_lds[32*64] (8KB);
    // phases 2b-3 use Ghi/Glo ushort[32*GPAD] (2*20,992B). max = 41,984B.
    __shared__ uint4 smem4[41984 / 16];
    float*  A2f      = (float*)smem4;
    float*  node_lds = A2f + Nq * 128;           // [j][f]
    ushort* Gh       = (ushort*)smem4;           // [i][GPAD]
    ushort* Gl       = Gh + Nq * GPAD;
    __shared__ float rowsum[Nq][4];

    const int b = blockIdx.x;
    const int t = threadIdx.x;

    // ---------------- Phase 1a: adjacency copy + stage ----------------
    const float* adj_b   = adj + (size_t)b * ADJ_B;
    float*       out_adj = out + (size_t)b * ADJ_B;
    #pragma unroll
    for (int it = 0; it < 5; ++it) {
        const int fi = (t + it * 256) * 4;
        float4 v = *(const float4*)(adj_b + fi);
        *(float4*)(out_adj + fi) = v;
        float vals[4] = {v.x, v.y, v.z, v.w};
        #pragma unroll
        for (int r = 0; r < 4; ++r) {
            const int idx = fi + r;              // i*160 + j*5 + e
            const int e  = idx % 5;
            const int ij = idx / 5;
            if (e > 0) {
                const int i = ij >> 5, j = ij & 31;
                A2f[a2idx(i, j * 4 + (e - 1))] = vals[r];
            }
        }
    }

    // ---------------- Phase 1b: node copy + stage (keep values in regs) ----------------
    const float* node_b   = node + (size_t)b * NODE_B;
    float*       out_node = out + ADJ_ELEMS + (size_t)b * NODE_B;
    float nv[8];
    #pragma unroll
    for (int it = 0; it < 2; ++it) {
        const int fi = (t + it * 256) * 4;
        float4 v = *(const float4*)(node_b + fi);
        *(float4*)(out_node + fi) = v;
        *(float4*)(node_lds + fi) = v;
        nv[it * 4 + 0] = v.x; nv[it * 4 + 1] = v.y; nv[it * 4 + 2] = v.z; nv[it * 4 + 3] = v.w;
    }
    __syncthreads();

    // ---------------- Phase 2a: GEMM1 fp32 (G = A_e @ node) ----------------
    float acc[32];
    {
        const int i  = t & 31;
        const int k0 = (t >> 5) * 32;   // k = e*64 + f, 32 consecutive per thread
        const int e  = k0 >> 6;
        const int f0 = k0 & 63;
        #pragma unroll
        for (int kk = 0; kk < 32; ++kk) acc[kk] = 0.f;
        #pragma unroll 4
        for (int j = 0; j < 32; ++j) {
            const float a = A2f[a2idx(i, j * 4 + e)];
            const float4* nrow = (const float4*)(node_lds + j * Fq + f0);
            #pragma unroll
            for (int q = 0; q < 8; ++q) {
                float4 n = nrow[q];
                acc[q*4+0] = fmaf(a, n.x, acc[q*4+0]);
                acc[q*4+1] = fmaf(a, n.y, acc[q*4+1]);
                acc[q*4+2] = fmaf(a, n.z, acc[q*4+2]);
                acc[q*4+3] = fmaf(a, n.w, acc[q*4+3]);
            }
        }
    }
    // rowsum_e[i] = sum_j A_e[i][j]  (exact b1-through-adjacency term)
    if (t < 128) {
        const int i = t >> 2, e = t & 3;
        float s = 0.f;
        #pragma unroll 4
        for (int j = 0; j < 32; ++j) s += A2f[a2idx(i, j * 4 + e)];
        rowsum[i][e] = s;
    }
    __syncthreads();   // all reads of A2f/node_lds complete

    // ---------------- Phase 2b: pack G + node into bf16 hi/lo LDS ----------------
    {
        const int i  = t & 31;
        const int k0 = (t >> 5) * 32;
        #pragma unroll
        for (int kk = 0; kk < 32; kk += 2) {
            const ushort hA = f2bf(acc[kk]);
            const ushort hB = f2bf(acc[kk + 1]);
            const ushort lA = f2bf(acc[kk]     - bf2f(hA));
            const ushort lB = f2bf(acc[kk + 1] - bf2f(hB));
            *(uint*)(Gh + i * GPAD + k0 + kk) = (uint)hA | ((uint)hB << 16);
            *(uint*)(Gl + i * GPAD + k0 + kk) = (uint)lA | ((uint)lB << 16);
        }
        // self-loop cols 256..319 = node (from registers)
        #pragma unroll
        for (int it = 0; it < 2; ++it) {
            const int fi = (t + it * 256) * 4;
            const int ni = fi >> 6, f = fi & 63;
            #pragma unroll
            for (int r = 0; r < 4; r += 2) {
                const ushort hA = f2bf(nv[it*4 + r]);
                const ushort hB = f2bf(nv[it*4 + r + 1]);
                const ushort lA = f2bf(nv[it*4 + r]     - bf2f(hA));
                const ushort lB = f2bf(nv[it*4 + r + 1] - bf2f(hB));
                *(uint*)(Gh + ni * GPAD + 256 + f + r) = (uint)hA | ((uint)hB << 16);
                *(uint*)(Gl + ni * GPAD + 256 + f + r) = (uint)lA | ((uint)lB << 16);
            }
        }
    }
    __syncthreads();

    // ---------------- Phase 3: GEMM2 via MFMA 16x16x32 bf16, split-3 ----------------
    const int w   = t >> 6;        // wave id 0..3 -> col tiles {2w, 2w+1}
    const int l   = t & 63;
    const int r16 = l & 15;
    const int khi = l >> 4;
    const int nq0 = w * 2, nq1 = nq0 + 1;

    f32x4 acc00 = {0.f,0.f,0.f,0.f}, acc01 = {0.f,0.f,0.f,0.f};
    f32x4 acc10 = {0.f,0.f,0.f,0.f}, acc11 = {0.f,0.f,0.f,0.f};

    #pragma unroll 2
    for (int kq = 0; kq < NKQ; ++kq) {
        const int kcol = kq * 32 + khi * 8;
        const bf16x8 aH0 = *(const bf16x8*)(Gh + r16        * GPAD + kcol);
        const bf16x8 aH1 = *(const bf16x8*)(Gh + (16 + r16) * GPAD + kcol);
        const bf16x8 aL0 = *(const bf16x8*)(Gl + r16        * GPAD + kcol);
        const bf16x8 aL1 = *(const bf16x8*)(Gl + (16 + r16) * GPAD + kcol);
        const bf16x8 bH0 = *(const bf16x8*)(wfH + (((kq * NNQ + nq0) * 64 + l) << 3));
        const bf16x8 bH1 = *(const bf16x8*)(wfH + (((kq * NNQ + nq1) * 64 + l) << 3));
        const bf16x8 bL0 = *(const bf16x8*)(wfL + (((kq * NNQ + nq0) * 64 + l) << 3));
        const bf16x8 bL1 = *(const bf16x8*)(wfL + (((kq * NNQ + nq1) * 64 + l) << 3));

        acc00 = __builtin_amdgcn_mfma_f32_16x16x32_bf16(aH0, bH0, acc00, 0, 0, 0);
        acc00 = __builtin_amdgcn_mfma_f32_16x16x32_bf16(aH0, bL0, acc00, 0, 0, 0);
        acc00 = __builtin_amdgcn_mfma_f32_16x16x32_bf16(aL0, bH0, acc00, 0, 0, 0);

        acc01 = __builtin_amdgcn_mfma_f32_16x16x32_bf16(aH0, bH1, acc01, 0, 0, 0);
        acc01 = __builtin_amdgcn_mfma_f32_16x16x32_bf16(aH0, bL1, acc01, 0, 0, 0);
        acc01 = __builtin_amdgcn_mfma_f32_16x16x32_bf16(aL0, bH1, acc01, 0, 0, 0);

        acc10 = __builtin_amdgcn_mfma_f32_16x16x32_bf16(aH1, bH0, acc10, 0, 0, 0);
        acc10 = __builtin_amdgcn_mfma_f32_16x16x32_bf16(aH1, bL0, acc10, 0, 0, 0);
        acc10 = __builtin_amdgcn_mfma_f32_16x16x32_bf16(aL1, bH0, acc10, 0, 0, 0);

        acc11 = __builtin_amdgcn_mfma_f32_16x16x32_bf16(aH1, bH1, acc11, 0, 0, 0);
        acc11 = __builtin_amdgcn_mfma_f32_16x16x32_bf16(aH1, bL1, acc11, 0, 0, 0);
        acc11 = __builtin_amdgcn_mfma_f32_16x16x32_bf16(aL1, bH1, acc11, 0, 0, 0);
    }

    // ---------------- Epilogue: bias + tanh + store ----------------
    float* out_b = out + OUT_OFF + (size_t)b * OUT_B;
    #pragma unroll
    for (int mh = 0; mh < 2; ++mh) {
        #pragma unroll
        for (int nqi = 0; nqi < 2; ++nqi) {
            const f32x4 a = (mh == 0) ? (nqi == 0 ? acc00 : acc01)
                                      : (nqi == 0 ? acc10 : acc11);
            const int u = (w * 2 + nqi) * 16 + r16;
            const float b2u = b2[u];
            const float b1u0 = b1[0 * Uq + u], b1u1 = b1[1 * Uq + u];
            const float b1u2 = b1[2 * Uq + u], b1u3 = b1[3 * Uq + u];
            #pragma unroll
            for (int r = 0; r < 4; ++r) {
                const int i = mh * 16 + khi * 4 + r;
                float pre = a[r] + b2u
                          + rowsum[i][0] * b1u0 + rowsum[i][1] * b1u1
                          + rowsum[i][2] * b1u2 + rowsum[i][3] * b1u3;
                out_b[i * Uq + u] = tanhf(pre);
            }
        }
    }
}

extern "C" void kernel_launch(void* const* d_in, const int* in_sizes, int n_in,
                              void* d_out, int out_size, void* d_ws, size_t ws_size,
                              hipStream_t stream) {
    const float* adj  = (const float*)d_in[0];
    const float* node = (const float*)d_in[1];
    const float* W1   = (const float*)d_in[2];
    const float* b1   = (const float*)d_in[3];
    const float* W2   = (const float*)d_in[4];
    const float* b2   = (const float*)d_in[5];
    float* out = (float*)d_out;

    ushort* wfH = (ushort*)d_ws;
    ushort* wfL = wfH + WF_ELEMS;

    hipLaunchKernelGGL(wfrag_kernel, dim3((WF_ELEMS + 255) / 256), dim3(256), 0, stream,
                       W1, W2, wfH, wfL);
    hipLaunchKernelGGL(gcn_kernel, dim3(Bq), dim3(256), 0, stream,
                       adj, node, b1, b2, wfH, wfL, out);
}

// Round 5
// 316.933 us; speedup vs baseline: 1.5939x; 1.1270x over previous
//
#include <hip/hip_runtime.h>
#include <math.h>

#define Bq 4096
#define Nq 32
#define Eq 5
#define Fq 64
#define Uq 128

constexpr int ADJ_ELEMS  = Bq * Nq * Nq * Eq;      // 20,971,520
constexpr int NODE_ELEMS = Bq * Nq * Fq;           // 8,388,608
constexpr int OUT_OFF    = ADJ_ELEMS + NODE_ELEMS; // 29,360,128
constexpr int ADJ_B  = Nq * Nq * Eq;  // 5120
constexpr int NODE_B = Nq * Fq;       // 2048
constexpr int OUT_B  = Nq * Uq;       // 4096
constexpr int NKQ = 10;               // 8 kq (G = A@node) + 2 kq (self-loop node)
constexpr int NNQ = Uq / 16;          // 8
constexpr int WF_ELEMS = NKQ * NNQ * 64 * 8;  // 40960 ushorts per table

typedef __attribute__((ext_vector_type(8))) short bf16x8;
typedef __attribute__((ext_vector_type(4))) float f32x4;

// ---- LDS map (ushort units) ----
// Union region [0,16384): GEMM1 operand frags live first, then G main planes.
constexpr int GHM_O  = 0;      // G hi main [32 rows][256 k] chunk-swizzled   (8192)
constexpr int GLM_O  = 8192;   // G lo main                                    (8192)
constexpr int ADJH_O = 0;      // adj B-frag hi [4e'][2mi][64 lane][8]         (4096)
constexpr int ADJL_O = 4096;   // adj B-frag lo                                (4096)
constexpr int NDH_O  = 8192;   // node A-frag hi [4fm][64 lane][8]             (2048)
constexpr int NDL_O  = 10240;  // node A-frag lo                               (2048)
// Non-union tail (written phase 1b, read GEMM2):
constexpr int GHS_O  = 16384;  // self-loop G hi [32][72]                      (2304)
constexpr int GLS_O  = 18688;  // self-loop G lo [32][72]                      (2304)
constexpr int RS_O   = 20992;  // rowsum f32[32][4]                            (256)
constexpr int SMEM_USH = 21248;                    // 42,496 B -> 3 blocks/CU

__device__ __forceinline__ ushort f2bf(float x) {  // RNE fp32->bf16
    uint u = __float_as_uint(x);
    return (ushort)((u + 0x7FFF + ((u >> 16) & 1)) >> 16);
}
__device__ __forceinline__ float bf2f(ushort h) { return __uint_as_float(((uint)h) << 16); }

#define MFMA(a, b, c) __builtin_amdgcn_mfma_f32_16x16x32_bf16((a), (b), (c), 0, 0, 0)

// ---------------------------------------------------------------------------
// Wcat -> B-fragment tables (hi/lo bf16) in d_ws (round-1 HW-verified):
//   lane l supplies B[kq*32 + (l>>4)*8 + e][nq*16 + (l&15)], e=0..7
// ---------------------------------------------------------------------------
__global__ void wfrag_kernel(const float* __restrict__ W1, const float* __restrict__ W2,
                             ushort* __restrict__ wfH, ushort* __restrict__ wfL) {
    const int tid = blockIdx.x * 256 + threadIdx.x;
    if (tid >= WF_ELEMS) return;
    const int k = tid >> 7;      // 0..319
    const int u = tid & 127;
    const float w = (k < 256) ? W1[k * Uq + u] : W2[(k - 256) * Uq + u];
    const ushort h  = f2bf(w);
    const ushort lo = f2bf(w - bf2f(h));
    const int kq = k >> 5, rem = k & 31;
    const int lane = ((rem >> 3) << 4) | (u & 15);
    const int nq = u >> 4;
    const int e = rem & 7;
    const int slot = (((kq * NNQ + nq) * 64 + lane) << 3) + e;
    wfH[slot] = h;
    wfL[slot] = lo;
}

__global__ __launch_bounds__(256, 3) void gcn_kernel(
    const float* __restrict__ adj, const float* __restrict__ node,
    const float* __restrict__ b1, const float* __restrict__ b2,
    const ushort* __restrict__ wfH, const ushort* __restrict__ wfL,
    float* __restrict__ out)
{
    __shared__ uint4 smem4[SMEM_USH / 8];
    ushort* sm = (ushort*)smem4;
    float* rowsumF = (float*)(sm + RS_O);

    const int b = blockIdx.x;
    const int t = threadIdx.x;
    const int l = t & 63, wv = t >> 6, g = l >> 4, l15 = l & 15;

    // ---------------- Phase 1a: adjacency copy + bf16 hi/lo B-frag scatter ----------------
    // Swapped GEMM1 uses adj^T as the B operand: lane = ((j>>3)<<4)|(i&15), e8 = j&7,
    // tile (e', mi=i>>4). Slot formula identical to the A-frag form by symmetry.
    const float* adj_b   = adj + (size_t)b * ADJ_B;
    float*       out_adj = out + (size_t)b * ADJ_B;
    #pragma unroll
    for (int it = 0; it < 5; ++it) {
        const int fi = (t + it * 256) * 4;
        float4 v = *(const float4*)(adj_b + fi);
        *(float4*)(out_adj + fi) = v;
        float vals[4] = {v.x, v.y, v.z, v.w};
        #pragma unroll
        for (int r = 0; r < 4; ++r) {
            const int idx = fi + r;              // i*160 + j*5 + e
            const int e  = idx % 5;
            const int ij = idx / 5;
            if (e > 0) {
                const int i = ij >> 5, j = ij & 31;
                const int slot = ((e - 1) * 2 + (i >> 4)) * 512
                               + ((((j >> 3) << 4) | (i & 15)) << 3) + (j & 7);
                const float x = vals[r];
                const ushort h  = f2bf(x);
                const ushort lo = f2bf(x - bf2f(h));
                sm[ADJH_O + slot] = h;
                sm[ADJL_O + slot] = lo;
            }
        }
    }

    // ---------------- Phase 1b: node copy + A-frag (GEMM1) + self-loop rows ----------------
    const float* node_b   = node + (size_t)b * NODE_B;
    float*       out_node = out + ADJ_ELEMS + (size_t)b * NODE_B;
    #pragma unroll
    for (int it = 0; it < 2; ++it) {
        const int fi = (t + it * 256) * 4;
        float4 v = *(const float4*)(node_b + fi);
        *(float4*)(out_node + fi) = v;
        const int j = fi >> 6, f0 = fi & 63;    // node row j, features f0..f0+3
        float vals[4] = {v.x, v.y, v.z, v.w};
        ushort hs[4], ls[4];
        #pragma unroll
        for (int r = 0; r < 4; ++r) {
            const int f = f0 + r;
            const float x = vals[r];
            const ushort h  = f2bf(x);
            const ushort lo = f2bf(x - bf2f(h));
            hs[r] = h; ls[r] = lo;
            // node^T as GEMM1 A operand: lane = ((j>>3)<<4)|(f&15), e8 = j&7, tile fm = f>>4
            const int slotA = (f >> 4) * 512 + ((((j >> 3) << 4) | (f & 15)) << 3) + (j & 7);
            sm[NDH_O + slotA] = h;
            sm[NDL_O + slotA] = lo;
        }
        // self-loop G rows: Gcat[i][256+f] = node[i][f], row-major [32][72]
        uint2 ph, pl;
        ph.x = (uint)hs[0] | ((uint)hs[1] << 16);
        ph.y = (uint)hs[2] | ((uint)hs[3] << 16);
        pl.x = (uint)ls[0] | ((uint)ls[1] << 16);
        pl.y = (uint)ls[2] | ((uint)ls[3] << 16);
        *(uint2*)(sm + GHS_O + j * 72 + f0) = ph;
        *(uint2*)(sm + GLS_O + j * 72 + f0) = pl;
    }
    __syncthreads();

    // ---------------- GEMM1 (swapped): C' = node^T @ A_e^T, wave wv -> e ----------------
    // C'[f][i] = sum_j node[j][f] * A_e[i][j] = G_e[i][f], so each lane ends up
    // holding 4 consecutive-k values of G for a single i -> cheap b64 handoff.
    const int e = wv;
    f32x4 c1t[4][2];   // [fm][mi]
    f32x4 rs2[2];
    #pragma unroll
    for (int fm = 0; fm < 4; ++fm)
        #pragma unroll
        for (int mi = 0; mi < 2; ++mi) c1t[fm][mi] = (f32x4){0.f, 0.f, 0.f, 0.f};
    rs2[0] = (f32x4){0.f, 0.f, 0.f, 0.f};
    rs2[1] = (f32x4){0.f, 0.f, 0.f, 0.f};
    {
        bf16x8 nAH[4], nAL[4], bAH[2], bAL[2], onesA;
        #pragma unroll
        for (int q = 0; q < 8; ++q) onesA[q] = (short)0x3F80;
        #pragma unroll
        for (int fm = 0; fm < 4; ++fm) {
            nAH[fm] = *(const bf16x8*)(sm + NDH_O + fm * 512 + l * 8);
            nAL[fm] = *(const bf16x8*)(sm + NDL_O + fm * 512 + l * 8);
        }
        #pragma unroll
        for (int mi = 0; mi < 2; ++mi) {
            bAH[mi] = *(const bf16x8*)(sm + ADJH_O + (e * 2 + mi) * 512 + l * 8);
            bAL[mi] = *(const bf16x8*)(sm + ADJL_O + (e * 2 + mi) * 512 + l * 8);
        }
        #pragma unroll
        for (int fm = 0; fm < 4; ++fm)
            #pragma unroll
            for (int mi = 0; mi < 2; ++mi) {
                c1t[fm][mi] = MFMA(nAH[fm], bAH[mi], c1t[fm][mi]);
                c1t[fm][mi] = MFMA(nAH[fm], bAL[mi], c1t[fm][mi]);
                c1t[fm][mi] = MFMA(nAL[fm], bAH[mi], c1t[fm][mi]);
            }
        #pragma unroll
        for (int mi = 0; mi < 2; ++mi) {
            rs2[mi] = MFMA(onesA, bAH[mi], rs2[mi]);   // every C row = rowsum_e[i]
            rs2[mi] = MFMA(onesA, bAL[mi], rs2[mi]);
        }
    }
    __syncthreads();   // GEMM1 frag reads done -> union region reusable as G planes

    // ---------------- Handoff: C' frags -> row-major G main (chunk-swizzled) ----------------
    // Lane l, tile (fm,mi): G[row = mi*16 + l15][kb..kb+3], kb = e*64 + fm*16 + g*4.
    #pragma unroll
    for (int fm = 0; fm < 4; ++fm) {
        #pragma unroll
        for (int mi = 0; mi < 2; ++mi) {
            const int row = mi * 16 + l15;
            const int kb  = e * 64 + fm * 16 + g * 4;
            const int chunk = kb >> 3;                       // 16B chunk index 0..31
            const int ush = row * 256 + (((chunk ^ (row & 7)) << 3) | ((kb & 4)));
            ushort h4[4], l4[4];
            #pragma unroll
            for (int r = 0; r < 4; ++r) {
                const float x = c1t[fm][mi][r];
                h4[r] = f2bf(x);
                l4[r] = f2bf(x - bf2f(h4[r]));
            }
            uint2 ph, pl;
            ph.x = (uint)h4[0] | ((uint)h4[1] << 16);
            ph.y = (uint)h4[2] | ((uint)h4[3] << 16);
            pl.x = (uint)l4[0] | ((uint)l4[1] << 16);
            pl.y = (uint)l4[2] | ((uint)l4[3] << 16);
            *(uint2*)(sm + GHM_O + ush) = ph;
            *(uint2*)(sm + GLM_O + ush) = pl;
        }
    }
    if (g == 0) {
        #pragma unroll
        for (int mi = 0; mi < 2; ++mi)
            rowsumF[(mi * 16 + l15) * 4 + e] = rs2[mi][0];
    }
    __syncthreads();

    // ---------------- GEMM2: out = Gcat @ Wcat via MFMA (split-3) ----------------
    const int nq0 = wv * 2, nq1 = nq0 + 1;
    f32x4 acc[2][2];
    #pragma unroll
    for (int mi = 0; mi < 2; ++mi)
        #pragma unroll
        for (int n = 0; n < 2; ++n) acc[mi][n] = (f32x4){0.f, 0.f, 0.f, 0.f};

    #pragma unroll
    for (int kq = 0; kq < 10; ++kq) {
        bf16x8 a2H[2], a2L[2];
        if (kq < 8) {
            #pragma unroll
            for (int mi = 0; mi < 2; ++mi) {
                const int row = mi * 16 + l15;
                const int ush = row * 256 + (((kq * 4 + g) ^ (row & 7)) << 3);
                a2H[mi] = *(const bf16x8*)(sm + GHM_O + ush);
                a2L[mi] = *(const bf16x8*)(sm + GLM_O + ush);
            }
        } else {
            const int ksl = kq - 8;
            #pragma unroll
            for (int mi = 0; mi < 2; ++mi) {
                const int row = mi * 16 + l15;
                const int ush = row * 72 + ksl * 32 + g * 8;
                a2H[mi] = *(const bf16x8*)(sm + GHS_O + ush);
                a2L[mi] = *(const bf16x8*)(sm + GLS_O + ush);
            }
        }
        const bf16x8 wH0 = *(const bf16x8*)(wfH + ((kq * 8 + nq0) * 64 + l) * 8);
        const bf16x8 wH1 = *(const bf16x8*)(wfH + ((kq * 8 + nq1) * 64 + l) * 8);
        const bf16x8 wL0 = *(const bf16x8*)(wfL + ((kq * 8 + nq0) * 64 + l) * 8);
        const bf16x8 wL1 = *(const bf16x8*)(wfL + ((kq * 8 + nq1) * 64 + l) * 8);
        #pragma unroll
        for (int mi = 0; mi < 2; ++mi) {
            acc[mi][0] = MFMA(a2H[mi], wH0, acc[mi][0]);
            acc[mi][0] = MFMA(a2H[mi], wL0, acc[mi][0]);
            acc[mi][0] = MFMA(a2L[mi], wH0, acc[mi][0]);
            acc[mi][1] = MFMA(a2H[mi], wH1, acc[mi][1]);
            acc[mi][1] = MFMA(a2H[mi], wL1, acc[mi][1]);
            acc[mi][1] = MFMA(a2L[mi], wH1, acc[mi][1]);
        }
    }

    // ---------------- Epilogue: + rowsum*b1 + b2, fast tanh, store ----------------
    float* out_b = out + OUT_OFF + (size_t)b * OUT_B;
    #pragma unroll
    for (int mi = 0; mi < 2; ++mi) {
        #pragma unroll
        for (int nqi = 0; nqi < 2; ++nqi) {
            const f32x4 a = acc[mi][nqi];
            const int u = (wv * 2 + nqi) * 16 + l15;
            const float b2u = b2[u];
            const float b10 = b1[0 * Uq + u], b11 = b1[1 * Uq + u];
            const float b12 = b1[2 * Uq + u], b13 = b1[3 * Uq + u];
            #pragma unroll
            for (int r = 0; r < 4; ++r) {
                const int i = mi * 16 + g * 4 + r;
                const float4 rsv = *(const float4*)(rowsumF + i * 4);
                float pre = a[r] + b2u + rsv.x * b10 + rsv.y * b11
                          + rsv.z * b12 + rsv.w * b13;
                const float ex = __expf(2.0f * pre);
                out_b[(size_t)i * Uq + u] = 1.0f - 2.0f * __builtin_amdgcn_rcpf(ex + 1.0f);
            }
        }
    }
}

extern "C" void kernel_launch(void* const* d_in, const int* in_sizes, int n_in,
                              void* d_out, int out_size, void* d_ws, size_t ws_size,
                              hipStream_t stream) {
    const float* adj  = (const float*)d_in[0];
    const float* node = (const float*)d_in[1];
    const float* W1   = (const float*)d_in[2];
    const float* b1   = (const float*)d_in[3];
    const float* W2   = (const float*)d_in[4];
    const float* b2   = (const float*)d_in[5];
    float* out = (float*)d_out;

    ushort* wfH = (ushort*)d_ws;
    ushort* wfL = wfH + WF_ELEMS;

    hipLaunchKernelGGL(wfrag_kernel, dim3((WF_ELEMS + 255) / 256), dim3(256), 0, stream,
                       W1, W2, wfH, wfL);
    hipLaunchKernelGGL(gcn_kernel, dim3(Bq), dim3(256), 0, stream,
                       adj, node, b1, b2, wfH, wfL, out);
}